// Round 3
// baseline (680.957 us; speedup 1.0000x reference)
//
#include <hip/hip_runtime.h>
#include <hip/hip_bf16.h>
#include <stdint.h>

#define BATCH 8
#define SEQ   4096
#define DM    512
#define HD    120

typedef __bf16   v8bf  __attribute__((ext_vector_type(8)));
typedef float    v4f   __attribute__((ext_vector_type(4)));
typedef int      i4    __attribute__((ext_vector_type(4)));
typedef uint32_t u32x2 __attribute__((ext_vector_type(2)));
typedef float    f32x4 __attribute__((ext_vector_type(4)));

static __device__ __forceinline__ ushort f2bf(float x) {
  uint32_t u = __builtin_bit_cast(uint32_t, x);
  return (ushort)((u + 0x7fffu + ((u >> 16) & 1u)) >> 16);
}

// -------------------------------------------------------------------------
// Kernel 1: ctx_n = normalize((q @ w_q^T + b_q) * wt) -> bf16 [B*S][128],
// LINEAR layout (row stride 256 B, cols 120..127 zero). 512 blocks x 256 thr.
// -------------------------------------------------------------------------
__global__ __launch_bounds__(256) void ctx_kernel(
    const float* __restrict__ q, const float* __restrict__ wq,
    const float* __restrict__ bq, const float* __restrict__ wt,
    ushort* __restrict__ ctx)
{
  __shared__ __align__(16) float qs[32][68];    // [kk][row]
  __shared__ __align__(16) float ws2[32][136];  // [kk][col]

  const int t  = threadIdx.x;
  const int tx = t & 31, ty = t >> 5;           // rows ty*8..+7, cols tx*4..+3
  const size_t row0 = (size_t)blockIdx.x * 64;
  const int qr = t >> 2, qk = (t & 3) * 8;

  float acc[8][4];
  #pragma unroll
  for (int j = 0; j < 8; ++j)
    #pragma unroll
    for (int i = 0; i < 4; ++i) acc[j][i] = 0.f;

  for (int k0 = 0; k0 < DM; k0 += 32) {
    __syncthreads();
    {
      f32x4 v0 = *(const f32x4*)&q[(row0 + qr) * DM + k0 + qk];
      f32x4 v1 = *(const f32x4*)&q[(row0 + qr) * DM + k0 + qk + 4];
      #pragma unroll
      for (int i = 0; i < 4; ++i) qs[qk + i][qr] = v0[i];
      #pragma unroll
      for (int i = 0; i < 4; ++i) qs[qk + 4 + i][qr] = v1[i];
    }
    #pragma unroll
    for (int i = 0; i < 16; ++i) {
      int flat = t + i * 256;
      int kk = flat & 31, c = flat >> 5;
      ws2[kk][c] = (c < HD) ? wq[c * DM + k0 + kk] : 0.f;
    }
    __syncthreads();
    #pragma unroll
    for (int kk = 0; kk < 32; ++kk) {
      f32x4 bv = *(const f32x4*)&ws2[kk][tx * 4];
      f32x4 a0 = *(const f32x4*)&qs[kk][ty * 8];
      f32x4 a1 = *(const f32x4*)&qs[kk][ty * 8 + 4];
      #pragma unroll
      for (int r = 0; r < 4; ++r)
        #pragma unroll
        for (int c = 0; c < 4; ++c) {
          acc[r][c]     = fmaf(a0[r], bv[c], acc[r][c]);
          acc[4 + r][c] = fmaf(a1[r], bv[c], acc[4 + r][c]);
        }
    }
  }

  float wtv[4], bqv[4];
  #pragma unroll
  for (int i = 0; i < 4; ++i) {
    int c = tx * 4 + i;
    wtv[i] = (c < HD) ? wt[c] : 0.f;
    bqv[i] = (c < HD) ? bq[c] : 0.f;
  }
  #pragma unroll
  for (int j = 0; j < 8; ++j) {
    int r = ty * 8 + j;
    float v[4]; float ss = 0.f;
    #pragma unroll
    for (int i = 0; i < 4; ++i) {
      v[i] = (acc[j][i] + bqv[i]) * wtv[i];
      ss = fmaf(v[i], v[i], ss);
    }
    #pragma unroll
    for (int xm = 1; xm < 32; xm <<= 1) ss += __shfl_xor(ss, xm, 64);
    float rinv = 1.f / fmaxf(sqrtf(ss), 1e-12f);
    uint32_t p0 = (uint32_t)f2bf(v[0] * rinv) | ((uint32_t)f2bf(v[1] * rinv) << 16);
    uint32_t p1 = (uint32_t)f2bf(v[2] * rinv) | ((uint32_t)f2bf(v[3] * rinv) << 16);
    u32x2 o = {p0, p1};
    *(u32x2*)((char*)ctx + (row0 + r) * 256 + tx * 8) = o;
  }
}

// -------------------------------------------------------------------------
// Kernel 2: wave-autonomous attention. Each wave: 16 q-rows x 4096 cols.
// No LDS, no barriers. Transposed MFMA D[p][q]: lane holds one q-row
// (col=lane&15), 8 contiguous-ish p (rows g*4+i, two 16-halves).
// Fixed softmax max = 1.0 (unit-vector dots). Two passes; mask bits via ws.
// -------------------------------------------------------------------------
#define MFMA(A, B, C) __builtin_amdgcn_mfma_f32_16x16x32_bf16(A, B, C, 0, 0, 0)

#define LDP(dst, jc) do {                                                     \
  const char* _p = ctxb + (size_t)((jc) * 32 + ln) * 256 + g * 16;            \
  dst[0] = *(const v8bf*)(_p);         dst[1] = *(const v8bf*)(_p + 64);      \
  dst[2] = *(const v8bf*)(_p + 128);   dst[3] = *(const v8bf*)(_p + 192);     \
  dst[4] = *(const v8bf*)(_p + 4096);  dst[5] = *(const v8bf*)(_p + 4160);    \
  dst[6] = *(const v8bf*)(_p + 4224);  dst[7] = *(const v8bf*)(_p + 4288);    \
} while (0)

#define LDM(dst, jc) do {                                                     \
  dst[0] = *(const i4*)(mrow + (jc) * 32 + g * 4);                            \
  dst[1] = *(const i4*)(mrow + (jc) * 32 + 16 + g * 4);                       \
} while (0)

#define QKT(pf, a0, a1) do {                                                  \
  a0 = (v4f){0.f, 0.f, 0.f, 0.f}; a1 = (v4f){0.f, 0.f, 0.f, 0.f};             \
  a0 = MFMA(pf[0], qf0, a0);  a1 = MFMA(pf[4], qf0, a1);                      \
  a0 = MFMA(pf[1], qf1, a0);  a1 = MFMA(pf[5], qf1, a1);                      \
  a0 = MFMA(pf[2], qf2, a0);  a1 = MFMA(pf[6], qf2, a1);                      \
  a0 = MFMA(pf[3], qf3, a0);  a1 = MFMA(pf[7], qf3, a1);                      \
} while (0)

#define STEPA(pf, mf, jc, SH) do {                                            \
  v4f a0, a1; QKT(pf, a0, a1);                                                \
  uint32_t tb = 0;                                                            \
  _Pragma("unroll")                                                           \
  for (int i = 0; i < 4; ++i) {                                               \
    float e0 = __expf(a0[i] - 1.f), e1 = __expf(a1[i] - 1.f);                 \
    lsum += (mf[0][i] ? e0 : 0.f) + (mf[1][i] ? e1 : 0.f);                    \
    tb |= (uint32_t)(mf[0][i] != 0) << i;                                     \
    tb |= (uint32_t)(mf[1][i] != 0) << (4 + i);                               \
  }                                                                           \
  ubits |= tb << (SH);                                                        \
  if ((SH) == 24) { wsb[((jc) >> 2) * 64 + lane] = ubits; ubits = 0; }        \
} while (0)

#define STEPB(pf, jc, SH) do {                                                \
  v4f a0, a1; QKT(pf, a0, a1);                                                \
  uint32_t bb = bcur >> (SH);                                                 \
  f32x4 o0, o1;                                                               \
  _Pragma("unroll")                                                           \
  for (int i = 0; i < 4; ++i) {                                               \
    o0[i] = ((bb >> i) & 1u)       ? __expf(a0[i] - 1.f) * lir : 0.f;         \
    o1[i] = ((bb >> (4 + i)) & 1u) ? __expf(a1[i] - 1.f) * lir : 0.f;         \
  }                                                                           \
  *(f32x4*)(orow + (size_t)(jc) * 32 + g * 4) = o0;                           \
  *(f32x4*)(orow + (size_t)(jc) * 32 + 16 + g * 4) = o1;                      \
} while (0)

__global__ __launch_bounds__(256) void attn_kernel(
    const ushort* __restrict__ ctx, const int* __restrict__ mask,
    uint32_t* __restrict__ wsbits, float* __restrict__ out)
{
  const int t    = threadIdx.x;
  const int b    = blockIdx.x & 7;          // batch -> XCD-pinned ctx panel
  const int w    = t >> 6, lane = t & 63;
  const int ln   = lane & 15, g = lane >> 4;
  const int qg   = (blockIdx.x >> 3) * 4 + w;       // 0..255 per batch
  const int qrow = qg * 16 + ln;                    // this lane's q-row
  const char* ctxb = (const char*)ctx + (size_t)b * SEQ * 256;
  const size_t obase = ((size_t)b * SEQ + qrow) * SEQ;
  const int*  __restrict__ mrow = mask + obase;
  float*      __restrict__ orow = out + obase;
  uint32_t*   __restrict__ wsb  = wsbits + ((size_t)blockIdx.x * 4 + w) * 2048;

  // persistent q fragments (B-operand): row qrow, 4 k-chunks
  const char* qp = ctxb + (size_t)qrow * 256 + g * 16;
  const v8bf qf0 = *(const v8bf*)(qp);
  const v8bf qf1 = *(const v8bf*)(qp + 64);
  const v8bf qf2 = *(const v8bf*)(qp + 128);
  const v8bf qf3 = *(const v8bf*)(qp + 192);

  v8bf pA[8], pB[8];
  i4   mA[2], mB[2];
  float lsum = 0.f;
  uint32_t ubits = 0;

  // ---------------- PASS A: l-sum + mask bits ----------------
  LDP(pA, 0); LDM(mA, 0);
  for (int j4 = 0; j4 < 128; j4 += 4) {
    LDP(pB, j4 + 1); LDM(mB, j4 + 1);
    STEPA(pA, mA, j4, 0);
    LDP(pA, j4 + 2); LDM(mA, j4 + 2);
    STEPA(pB, mB, j4 + 1, 8);
    LDP(pB, j4 + 3); LDM(mB, j4 + 3);
    STEPA(pA, mA, j4 + 2, 16);
    if (j4 + 4 < 128) { LDP(pA, j4 + 4); LDM(mA, j4 + 4); }
    STEPA(pB, mB, j4 + 3, 24);
  }

  // l reduce over the 4 g-groups (lanes with same ln share q-row)
  lsum += __shfl_xor(lsum, 16, 64);
  lsum += __shfl_xor(lsum, 32, 64);
  const float lir = (lsum > 0.f) ? (1.f / lsum) : 0.f;

  // ensure our wsb stores are visible to our own loads
  asm volatile("s_waitcnt vmcnt(0)" ::: "memory");

  // ---------------- PASS B: recompute, scale, write ----------------
  uint32_t bcur = wsb[lane];
  LDP(pA, 0);
  for (int j4 = 0; j4 < 128; j4 += 4) {
    uint32_t bnxt = (j4 + 4 < 128) ? wsb[((j4 >> 2) + 1) * 64 + lane] : 0u;
    LDP(pB, j4 + 1);
    STEPB(pA, j4, 0);
    LDP(pA, j4 + 2);
    STEPB(pB, j4 + 1, 8);
    LDP(pB, j4 + 3);
    STEPB(pA, j4 + 2, 16);
    if (j4 + 4 < 128) LDP(pA, j4 + 4);
    STEPB(pB, j4 + 3, 24);
    bcur = bnxt;
  }
}

// -------------------------------------------------------------------------
extern "C" void kernel_launch(void* const* d_in, const int* in_sizes, int n_in,
                              void* d_out, int out_size, void* d_ws, size_t ws_size,
                              hipStream_t stream) {
  const float* query = (const float*)d_in[0];
  const int*   mask  = (const int*)d_in[1];
  const float* w_q   = (const float*)d_in[2];
  const float* b_q   = (const float*)d_in[3];
  const float* wt    = (const float*)d_in[4];
  float* out = (float*)d_out;

  ushort*   ctx    = (ushort*)d_ws;                              // 8.4 MB
  uint32_t* wsbits = (uint32_t*)((char*)d_ws + (16u << 20));     // +16 MB

  ctx_kernel<<<dim3(BATCH * SEQ / 64), dim3(256), 0, stream>>>(query, w_q, b_q, wt, ctx);
  attn_kernel<<<dim3(512), dim3(256), 0, stream>>>(ctx, mask, wsbits, out);
}

// Round 4
// 438.303 us; speedup vs baseline: 1.5536x; 1.5536x over previous
//
#include <hip/hip_runtime.h>
#include <hip/hip_bf16.h>
#include <stdint.h>

#define BATCH 8
#define SEQ   4096
#define DM    512
#define HD    120

typedef __bf16   v8bf  __attribute__((ext_vector_type(8)));
typedef float    v4f   __attribute__((ext_vector_type(4)));
typedef int      i4    __attribute__((ext_vector_type(4)));
typedef uint32_t u32x2 __attribute__((ext_vector_type(2)));
typedef uint32_t u32x4 __attribute__((ext_vector_type(4)));
typedef float    f32x4 __attribute__((ext_vector_type(4)));

static __device__ __forceinline__ ushort f2bf(float x) {
  uint32_t u = __builtin_bit_cast(uint32_t, x);
  return (ushort)((u + 0x7fffu + ((u >> 16) & 1u)) >> 16);
}

// async global->LDS, 16B/lane. LDS base wave-uniform; global addr per-lane.
static __device__ __forceinline__ void gld16(const void* g, void* l) {
  __builtin_amdgcn_global_load_lds(
      (const __attribute__((address_space(1))) uint32_t*)g,
      (__attribute__((address_space(3))) uint32_t*)l, 16, 0, 0);
}

// -------------------------------------------------------------------------
// Kernel 1: ctx_n = normalize((q @ w_q^T + b_q) * wt) -> bf16 [B*S][128],
// stored PRE-SWIZZLED: byte-in-row = (slot*16) ^ ((row&7)<<4), slot = 16B
// k-chunk. Linear global_load_lds staging then lands bank-conflict-free.
// -------------------------------------------------------------------------
__global__ __launch_bounds__(256) void ctx_kernel(
    const float* __restrict__ q, const float* __restrict__ wq,
    const float* __restrict__ bq, const float* __restrict__ wt,
    ushort* __restrict__ ctx)
{
  __shared__ __align__(16) float qs[32][68];    // [kk][row]
  __shared__ __align__(16) float ws2[32][136];  // [kk][col]

  const int t  = threadIdx.x;
  const int tx = t & 31, ty = t >> 5;           // rows ty*8..+7, cols tx*4..+3
  const size_t row0 = (size_t)blockIdx.x * 64;
  const int qr = t >> 2, qk = (t & 3) * 8;

  float acc[8][4];
  #pragma unroll
  for (int j = 0; j < 8; ++j)
    #pragma unroll
    for (int i = 0; i < 4; ++i) acc[j][i] = 0.f;

  for (int k0 = 0; k0 < DM; k0 += 32) {
    __syncthreads();
    {
      f32x4 v0 = *(const f32x4*)&q[(row0 + qr) * DM + k0 + qk];
      f32x4 v1 = *(const f32x4*)&q[(row0 + qr) * DM + k0 + qk + 4];
      #pragma unroll
      for (int i = 0; i < 4; ++i) qs[qk + i][qr] = v0[i];
      #pragma unroll
      for (int i = 0; i < 4; ++i) qs[qk + 4 + i][qr] = v1[i];
    }
    #pragma unroll
    for (int i = 0; i < 16; ++i) {
      int flat = t + i * 256;
      int kk = flat & 31, c = flat >> 5;
      ws2[kk][c] = (c < HD) ? wq[c * DM + k0 + kk] : 0.f;
    }
    __syncthreads();
    #pragma unroll
    for (int kk = 0; kk < 32; ++kk) {
      f32x4 bv = *(const f32x4*)&ws2[kk][tx * 4];
      f32x4 a0 = *(const f32x4*)&qs[kk][ty * 8];
      f32x4 a1 = *(const f32x4*)&qs[kk][ty * 8 + 4];
      #pragma unroll
      for (int r = 0; r < 4; ++r)
        #pragma unroll
        for (int c = 0; c < 4; ++c) {
          acc[r][c]     = fmaf(a0[r], bv[c], acc[r][c]);
          acc[4 + r][c] = fmaf(a1[r], bv[c], acc[4 + r][c]);
        }
    }
  }

  float wtv[4], bqv[4];
  #pragma unroll
  for (int i = 0; i < 4; ++i) {
    int c = tx * 4 + i;
    wtv[i] = (c < HD) ? wt[c] : 0.f;
    bqv[i] = (c < HD) ? bq[c] : 0.f;
  }
  #pragma unroll
  for (int j = 0; j < 8; ++j) {
    int r = ty * 8 + j;
    float v[4]; float ss = 0.f;
    #pragma unroll
    for (int i = 0; i < 4; ++i) {
      v[i] = (acc[j][i] + bqv[i]) * wtv[i];
      ss = fmaf(v[i], v[i], ss);
    }
    #pragma unroll
    for (int xm = 1; xm < 32; xm <<= 1) ss += __shfl_xor(ss, xm, 64);
    float rinv = 1.f / fmaxf(sqrtf(ss), 1e-12f);
    uint32_t p0 = (uint32_t)f2bf(v[0] * rinv) | ((uint32_t)f2bf(v[1] * rinv) << 16);
    uint32_t p1 = (uint32_t)f2bf(v[2] * rinv) | ((uint32_t)f2bf(v[3] * rinv) << 16);
    u32x2 o = {p0, p1};
    char* dst = (char*)ctx + (row0 + r) * 256 +
                (((tx >> 1) * 16) ^ ((r & 7) << 4)) + (tx & 1) * 8;
    *(u32x2*)dst = o;
  }
}

// -------------------------------------------------------------------------
// Kernel 2: 512 blocks x 256 thr (4 waves). Wave owns 16 q-rows (Q frags
// persistent in regs); the 4 waves share a double-buffered 64-p-row LDS tile
// (global_load_lds from pre-swizzled ctx). Transposed MFMA D[p][q]: lane =
// one q-row (col=ln), p contiguous per acc -> i4 mask loads, f32x4 out
// stores, l-reduce = 2 shfls. Fixed softmax max = 1.0. Two passes; mask bits
// round-trip via ws (L2).
// -------------------------------------------------------------------------
#define MFMA(A, B, C) __builtin_amdgcn_mfma_f32_16x16x32_bf16(A, B, C, 0, 0, 0)

static __device__ __forceinline__ v8bf ldfrag(const char* base, int row, int slot) {
  int byte = row * 256 + ((slot * 16) ^ ((row & 7) << 4));
  return __builtin_bit_cast(v8bf, *(const u32x4*)(base + byte));
}

#define STAGE(buf, j) do {                                                    \
  const char* _gs = ctxb + (size_t)(j) * 64 * 256;                            \
  _Pragma("unroll")                                                           \
  for (int _i = 0; _i < 4; ++_i)                                              \
    gld16(_gs + (w * 4 + _i) * 1024 + lane * 16, (buf) + (w * 4 + _i) * 1024);\
} while (0)

#define LDM(dst, j) do {                                                      \
  _Pragma("unroll")                                                           \
  for (int _t = 0; _t < 4; ++_t)                                              \
    dst[_t] = *(const i4*)(mrow + (size_t)(j) * 64 + _t * 16 + g * 4);        \
} while (0)

#define QKT(buf, acc) do {                                                    \
  _Pragma("unroll")                                                           \
  for (int _t = 0; _t < 4; ++_t) {                                            \
    acc[_t] = (v4f){0.f, 0.f, 0.f, 0.f};                                      \
    _Pragma("unroll")                                                         \
    for (int _k = 0; _k < 4; ++_k) {                                          \
      v8bf _a = ldfrag(buf, _t * 16 + ln, _k * 4 + g);                        \
      acc[_t] = MFMA(_a, qf[_k], acc[_t]);                                    \
    }                                                                         \
  }                                                                           \
} while (0)

__global__ __launch_bounds__(256) void attn_kernel(
    const ushort* __restrict__ ctx, const int* __restrict__ mask,
    uint32_t* __restrict__ wsbits, float* __restrict__ out)
{
  __shared__ __align__(16) char lds[32768];
  char* B0 = lds;
  char* B1 = lds + 16384;

  const int t    = threadIdx.x;
  const int b    = blockIdx.x & 7;              // batch -> XCD-pinned panel
  const int tile = blockIdx.x >> 3;
  const int w    = t >> 6, lane = t & 63;
  const int ln   = lane & 15, g = lane >> 4;
  const int qrow = tile * 64 + w * 16 + ln;     // this lane's q-row
  const char* ctxb = (const char*)ctx + (size_t)b * SEQ * 256;
  const int*  __restrict__ mrow = mask + ((size_t)b * SEQ + qrow) * SEQ;
  float*      __restrict__ orow = out + ((size_t)b * SEQ + qrow) * SEQ;
  uint32_t*   __restrict__ wsb  = wsbits + ((size_t)blockIdx.x * 4 + w) * 2048;

  // persistent Q fragments (B-operand), from pre-swizzled ctx
  v8bf qf[4];
  #pragma unroll
  for (int kk = 0; kk < 4; ++kk) {
    int slot = kk * 4 + g;
    qf[kk] = *(const v8bf*)(ctxb + (size_t)qrow * 256 +
                            ((slot * 16) ^ ((qrow & 7) << 4)));
  }

  float lsum = 0.f;
  uint32_t lob = 0;
  i4 mc[4], mn[4];

  // ---------------- PASS A: l-sum + mask bits ----------------
  STAGE(B0, 0);
  LDM(mc, 0);
  __syncthreads();

  for (int j = 0; j < 64; ++j) {
    char* cur = (j & 1) ? B1 : B0;
    char* nxt = (j & 1) ? B0 : B1;
    if (j < 63) { STAGE(nxt, j + 1); LDM(mn, j + 1); }

    v4f acc[4];
    QKT(cur, acc);

    uint32_t tb = 0;
    #pragma unroll
    for (int t2 = 0; t2 < 4; ++t2)
      #pragma unroll
      for (int i = 0; i < 4; ++i) {
        float e = __expf(acc[t2][i] - 1.0f);
        lsum += mc[t2][i] ? e : 0.f;
        tb |= (uint32_t)(mc[t2][i] != 0) << (t2 * 4 + i);
      }
    if (j & 1) wsb[(j >> 1) * 64 + lane] = lob | (tb << 16);
    else       lob = tb;

    if (j < 63) {
      #pragma unroll
      for (int t2 = 0; t2 < 4; ++t2) mc[t2] = mn[t2];
    }
    __syncthreads();
  }

  // l-reduce over the 4 g-groups (lanes with same ln share a q-row)
  lsum += __shfl_xor(lsum, 16, 64);
  lsum += __shfl_xor(lsum, 32, 64);
  const float lir = (lsum > 0.f) ? (1.f / lsum) : 0.f;

  // make our wsb stores visible to our own loads
  asm volatile("s_waitcnt vmcnt(0)" ::: "memory");

  // ---------------- PASS B: recompute, scale, write ----------------
  uint32_t bcur = wsb[lane];
  uint32_t bnxt = 0;
  STAGE(B0, 0);
  __syncthreads();

  for (int j = 0; j < 64; ++j) {
    char* cur = (j & 1) ? B1 : B0;
    char* nxt = (j & 1) ? B0 : B1;
    if (j < 63) STAGE(nxt, j + 1);
    if (!(j & 1) && j < 62) bnxt = wsb[((j >> 1) + 1) * 64 + lane];

    v4f acc[4];
    QKT(cur, acc);

    uint32_t bb = bcur >> ((j & 1) * 16);
    #pragma unroll
    for (int t2 = 0; t2 < 4; ++t2) {
      f32x4 o;
      #pragma unroll
      for (int i = 0; i < 4; ++i)
        o[i] = ((bb >> (t2 * 4 + i)) & 1u) ? __expf(acc[t2][i] - 1.0f) * lir : 0.f;
      *(f32x4*)(orow + (size_t)j * 64 + t2 * 16 + g * 4) = o;
    }
    if (j & 1) bcur = bnxt;
    __syncthreads();
  }
}

// -------------------------------------------------------------------------
extern "C" void kernel_launch(void* const* d_in, const int* in_sizes, int n_in,
                              void* d_out, int out_size, void* d_ws, size_t ws_size,
                              hipStream_t stream) {
  const float* query = (const float*)d_in[0];
  const int*   mask  = (const int*)d_in[1];
  const float* w_q   = (const float*)d_in[2];
  const float* b_q   = (const float*)d_in[3];
  const float* wt    = (const float*)d_in[4];
  float* out = (float*)d_out;

  ushort*   ctx    = (ushort*)d_ws;                              // 8.4 MB
  uint32_t* wsbits = (uint32_t*)((char*)d_ws + (16u << 20));     // +16 MB

  ctx_kernel<<<dim3(BATCH * SEQ / 64), dim3(256), 0, stream>>>(query, w_q, b_q, wt, ctx);
  attn_kernel<<<dim3(512), dim3(256), 0, stream>>>(ctx, mask, wsbits, out);
}

// Round 5
// 395.705 us; speedup vs baseline: 1.7209x; 1.1077x over previous
//
#include <hip/hip_runtime.h>
#include <hip/hip_bf16.h>
#include <stdint.h>

#define BATCH 8
#define SEQ   4096
#define DM    512
#define HD    120

typedef __bf16   v8bf  __attribute__((ext_vector_type(8)));
typedef float    v4f   __attribute__((ext_vector_type(4)));
typedef int      i4    __attribute__((ext_vector_type(4)));
typedef uint32_t u32x2 __attribute__((ext_vector_type(2)));
typedef uint32_t u32x4 __attribute__((ext_vector_type(4)));
typedef float    f32x4 __attribute__((ext_vector_type(4)));

static __device__ __forceinline__ ushort f2bf(float x) {
  uint32_t u = __builtin_bit_cast(uint32_t, x);
  return (ushort)((u + 0x7fffu + ((u >> 16) & 1u)) >> 16);
}

// -------------------------------------------------------------------------
// prep_kernel, 1024 blocks x 256 thr. Odd blocks: compress 64 mask rows ->
// 1 bit/elem (BW-bound). Even blocks: ctx GEMM (VALU-bound), ctx stored
// PRE-SWIZZLED: byte-in-row = (slot*16) ^ ((row&7)<<4). Heterogeneous blocks
// co-resident -> memory stream overlaps VALU GEMM.
// -------------------------------------------------------------------------
__global__ __launch_bounds__(256) void prep_kernel(
    const float* __restrict__ q, const float* __restrict__ wq,
    const float* __restrict__ bq, const float* __restrict__ wt,
    const int* __restrict__ mask, ushort* __restrict__ ctx,
    uint32_t* __restrict__ bits)
{
  __shared__ __align__(16) float qs[32][68];    // [kk][row]
  __shared__ __align__(16) float ws2[32][136];  // [kk][col]

  const int t = threadIdx.x;
  const int cb = blockIdx.x >> 1;

  if (blockIdx.x & 1) {
    // ---- mask compression: rows cb*64 .. +63 (flat over B*S) ----
    const size_t row0 = (size_t)cb * 64;
    const int rhalf = t >> 7;            // 0..1
    const int pw    = t & 127;           // 32-bit word within row
    const int* mbase = mask + row0 * SEQ;
    uint32_t* bbase  = bits + row0 * 128;
    for (int s = 0; s < 32; ++s) {
      int row = s * 2 + rhalf;
      const int* mp = mbase + (size_t)row * SEQ + pw * 32;
      uint32_t wd = 0;
      #pragma unroll
      for (int k = 0; k < 8; ++k) {
        i4 m = *(const i4*)(mp + k * 4);
        wd |= (uint32_t)(m.x != 0) << (k * 4);
        wd |= (uint32_t)(m.y != 0) << (k * 4 + 1);
        wd |= (uint32_t)(m.z != 0) << (k * 4 + 2);
        wd |= (uint32_t)(m.w != 0) << (k * 4 + 3);
      }
      bbase[(size_t)row * 128 + pw] = wd;
    }
    return;
  }

  // ---- ctx GEMM: rows cb*64 .. +63 ----
  const int tx = t & 31, ty = t >> 5;
  const size_t row0 = (size_t)cb * 64;
  const int qr = t >> 2, qk = (t & 3) * 8;

  float acc[8][4];
  #pragma unroll
  for (int j = 0; j < 8; ++j)
    #pragma unroll
    for (int i = 0; i < 4; ++i) acc[j][i] = 0.f;

  for (int k0 = 0; k0 < DM; k0 += 32) {
    __syncthreads();
    {
      f32x4 v0 = *(const f32x4*)&q[(row0 + qr) * DM + k0 + qk];
      f32x4 v1 = *(const f32x4*)&q[(row0 + qr) * DM + k0 + qk + 4];
      #pragma unroll
      for (int i = 0; i < 4; ++i) qs[qk + i][qr] = v0[i];
      #pragma unroll
      for (int i = 0; i < 4; ++i) qs[qk + 4 + i][qr] = v1[i];
    }
    #pragma unroll
    for (int i = 0; i < 16; ++i) {
      int flat = t + i * 256;
      int kk = flat & 31, c = flat >> 5;
      ws2[kk][c] = (c < HD) ? wq[c * DM + k0 + kk] : 0.f;
    }
    __syncthreads();
    #pragma unroll
    for (int kk = 0; kk < 32; ++kk) {
      f32x4 bv = *(const f32x4*)&ws2[kk][tx * 4];
      f32x4 a0 = *(const f32x4*)&qs[kk][ty * 8];
      f32x4 a1 = *(const f32x4*)&qs[kk][ty * 8 + 4];
      #pragma unroll
      for (int r = 0; r < 4; ++r)
        #pragma unroll
        for (int c = 0; c < 4; ++c) {
          acc[r][c]     = fmaf(a0[r], bv[c], acc[r][c]);
          acc[4 + r][c] = fmaf(a1[r], bv[c], acc[4 + r][c]);
        }
    }
  }

  float wtv[4], bqv[4];
  #pragma unroll
  for (int i = 0; i < 4; ++i) {
    int c = tx * 4 + i;
    wtv[i] = (c < HD) ? wt[c] : 0.f;
    bqv[i] = (c < HD) ? bq[c] : 0.f;
  }
  #pragma unroll
  for (int j = 0; j < 8; ++j) {
    int r = ty * 8 + j;
    float v[4]; float ss = 0.f;
    #pragma unroll
    for (int i = 0; i < 4; ++i) {
      v[i] = (acc[j][i] + bqv[i]) * wtv[i];
      ss = fmaf(v[i], v[i], ss);
    }
    #pragma unroll
    for (int xm = 1; xm < 32; xm <<= 1) ss += __shfl_xor(ss, xm, 64);
    float rinv = 1.f / fmaxf(sqrtf(ss), 1e-12f);
    uint32_t p0 = (uint32_t)f2bf(v[0] * rinv) | ((uint32_t)f2bf(v[1] * rinv) << 16);
    uint32_t p1 = (uint32_t)f2bf(v[2] * rinv) | ((uint32_t)f2bf(v[3] * rinv) << 16);
    u32x2 o = {p0, p1};
    char* dst = (char*)ctx + (row0 + r) * 256 +
                (((tx >> 1) * 16) ^ ((r & 7) << 4)) + (tx & 1) * 8;
    *(u32x2*)dst = o;
  }
}

// -------------------------------------------------------------------------
// attn_kernel: 512 blocks x 4 waves. Wave = 16 q-rows (Q frags persistent);
// waves share double-buffered 64-p-row tiles, REG-STAGED (global->reg->
// ds_write) so no vmcnt(0) drain ever executes in the loop; raw s_barrier
// with hand lgkmcnt(0) only. Mask = precomputed bits (L2). Fixed max = 1.0.
// -------------------------------------------------------------------------
#define MFMA(A, B, C) __builtin_amdgcn_mfma_f32_16x16x32_bf16(A, B, C, 0, 0, 0)

static __device__ __forceinline__ v8bf ldfrag(const char* base, int row, int slot) {
  int byte = row * 256 + ((slot * 16) ^ ((row & 7) << 4));
  return __builtin_bit_cast(v8bf, *(const u32x4*)(base + byte));
}

#define STG_LOAD(R, j) do {                                                   \
  const char* _g = ctxb + (size_t)(j) * 16384 + w * 4096 + lane * 16;         \
  R##0 = *(const u32x4*)(_g);        R##1 = *(const u32x4*)(_g + 1024);       \
  R##2 = *(const u32x4*)(_g + 2048); R##3 = *(const u32x4*)(_g + 3072);       \
} while (0)

#define STG_WRITE(R, buf) do {                                                \
  char* _l = (buf) + w * 4096 + lane * 16;                                    \
  *(u32x4*)(_l)        = R##0;  *(u32x4*)(_l + 1024) = R##1;                  \
  *(u32x4*)(_l + 2048) = R##2;  *(u32x4*)(_l + 3072) = R##3;                  \
} while (0)

#define QKT(buf, acc) do {                                                    \
  _Pragma("unroll")                                                           \
  for (int _t = 0; _t < 4; ++_t) {                                            \
    acc[_t] = (v4f){0.f, 0.f, 0.f, 0.f};                                      \
    _Pragma("unroll")                                                         \
    for (int _k = 0; _k < 4; ++_k) {                                          \
      v8bf _a = ldfrag(buf, _t * 16 + ln, _k * 4 + g);                        \
      acc[_t] = MFMA(_a, qf[_k], acc[_t]);                                    \
    }                                                                         \
  }                                                                           \
} while (0)

#define EPIA(BW) do {                                                         \
  _Pragma("unroll")                                                           \
  for (int _t2 = 0; _t2 < 4; ++_t2) {                                         \
    uint32_t nib = ((_t2 < 2 ? (BW).x : (BW).y) >> ((_t2 & 1) * 16 + g * 4)); \
    _Pragma("unroll")                                                         \
    for (int _i = 0; _i < 4; ++_i) {                                          \
      float e = __expf(acc[_t2][_i] - 1.0f);                                  \
      lsum += ((nib >> _i) & 1u) ? e : 0.f;                                   \
    }                                                                         \
  }                                                                           \
} while (0)

#define EPIB(BW, j) do {                                                      \
  _Pragma("unroll")                                                           \
  for (int _t2 = 0; _t2 < 4; ++_t2) {                                         \
    uint32_t nib = ((_t2 < 2 ? (BW).x : (BW).y) >> ((_t2 & 1) * 16 + g * 4)); \
    f32x4 o;                                                                  \
    _Pragma("unroll")                                                         \
    for (int _i = 0; _i < 4; ++_i)                                            \
      o[_i] = ((nib >> _i) & 1u) ? __expf(acc[_t2][_i] - 1.0f) * lir : 0.f;   \
    *(f32x4*)(orow + (size_t)(j) * 64 + _t2 * 16 + g * 4) = o;                \
  }                                                                           \
} while (0)

#define BAR() do {                                                            \
  asm volatile("s_waitcnt lgkmcnt(0)" ::: "memory");                          \
  __builtin_amdgcn_s_barrier();                                               \
  __builtin_amdgcn_sched_barrier(0);                                          \
} while (0)

__global__ __launch_bounds__(256) void attn_kernel(
    const ushort* __restrict__ ctx, const uint32_t* __restrict__ bits,
    float* __restrict__ out)
{
  __shared__ __align__(16) char lds[32768];
  char* B0 = lds;
  char* B1 = lds + 16384;

  const int t    = threadIdx.x;
  const int b    = blockIdx.x & 7;              // batch -> XCD-pinned panel
  const int tile = blockIdx.x >> 3;
  const int w    = t >> 6, lane = t & 63;
  const int ln   = lane & 15, g = lane >> 4;
  const int qrow = tile * 64 + w * 16 + ln;
  const char* ctxb = (const char*)ctx + (size_t)b * SEQ * 256;
  const uint32_t* __restrict__ brow = bits + ((size_t)b * SEQ + qrow) * 128;
  float*          __restrict__ orow = out + ((size_t)b * SEQ + qrow) * SEQ;

  // persistent Q fragments (B-operand), from pre-swizzled ctx
  v8bf qf[4];
  #pragma unroll
  for (int kk = 0; kk < 4; ++kk) {
    int slot = kk * 4 + g;
    qf[kk] = *(const v8bf*)(ctxb + (size_t)qrow * 256 +
                            ((slot * 16) ^ ((qrow & 7) << 4)));
  }

  u32x4 sA0, sA1, sA2, sA3, sB0, sB1, sB2, sB3;
  u32x2 bw0 = {0, 0}, bw1 = {0, 0}, bwn0 = {0, 0}, bwn1 = {0, 0};
  float lsum = 0.f;

  // ---------------- PASS A: masked sum of exp(s-1) ----------------
  STG_LOAD(sA, 0);
  bw0 = *(const u32x2*)(brow);
  bw1 = *(const u32x2*)(brow + 2);
  STG_WRITE(sA, B0);
  STG_LOAD(sB, 1);
  __syncthreads();

  for (int jj = 0; jj < 64; jj += 2) {
    v4f acc[4];
    if (jj + 2 < 64) { STG_LOAD(sA, jj + 2); bwn0 = *(const u32x2*)(brow + (jj + 2) * 2); }
    QKT(B0, acc);
    STG_WRITE(sB, B1);
    EPIA(bw0);
    BAR();

    if (jj + 3 < 64) { STG_LOAD(sB, jj + 3); bwn1 = *(const u32x2*)(brow + (jj + 3) * 2); }
    QKT(B1, acc);
    if (jj + 2 < 64) STG_WRITE(sA, B0);
    EPIA(bw1);
    bw0 = bwn0; bw1 = bwn1;
    BAR();
  }

  // l-reduce over the 4 g-groups (lanes sharing a q-row)
  lsum += __shfl_xor(lsum, 16, 64);
  lsum += __shfl_xor(lsum, 32, 64);
  const float lir = (lsum > 0.f) ? (1.f / lsum) : 0.f;

  // ---------------- PASS B: recompute, scale, write ----------------
  STG_LOAD(sA, 0);
  bw0 = *(const u32x2*)(brow);
  bw1 = *(const u32x2*)(brow + 2);
  STG_WRITE(sA, B0);
  STG_LOAD(sB, 1);
  __syncthreads();

  for (int jj = 0; jj < 64; jj += 2) {
    v4f acc[4];
    if (jj + 2 < 64) { STG_LOAD(sA, jj + 2); bwn0 = *(const u32x2*)(brow + (jj + 2) * 2); }
    QKT(B0, acc);
    STG_WRITE(sB, B1);
    EPIB(bw0, jj);
    BAR();

    if (jj + 3 < 64) { STG_LOAD(sB, jj + 3); bwn1 = *(const u32x2*)(brow + (jj + 3) * 2); }
    QKT(B1, acc);
    if (jj + 2 < 64) STG_WRITE(sA, B0);
    EPIB(bw1, jj + 1);
    bw0 = bwn0; bw1 = bwn1;
    BAR();
  }
}

// -------------------------------------------------------------------------
extern "C" void kernel_launch(void* const* d_in, const int* in_sizes, int n_in,
                              void* d_out, int out_size, void* d_ws, size_t ws_size,
                              hipStream_t stream) {
  const float* query = (const float*)d_in[0];
  const int*   mask  = (const int*)d_in[1];
  const float* w_q   = (const float*)d_in[2];
  const float* b_q   = (const float*)d_in[3];
  const float* wt    = (const float*)d_in[4];
  float* out = (float*)d_out;

  ushort*   ctx  = (ushort*)d_ws;                              // 8 MB
  uint32_t* bits = (uint32_t*)((char*)d_ws + (16u << 20));     // +16 MB

  prep_kernel<<<dim3(1024), dim3(256), 0, stream>>>(query, w_q, b_q, wt, mask, ctx, bits);
  attn_kernel<<<dim3(512), dim3(256), 0, stream>>>(ctx, bits, out);
}